// Round 4
// baseline (759.663 us; speedup 1.0000x reference)
//
#include <hip/hip_runtime.h>
#include <math.h>

#define N_EDGES 4096
#define NN1 256
#define NN2 128

// ---------------- reduction helpers ----------------
template<int NT>
__device__ inline float block_sum(float v, float* red, int t){
  red[t] = v; __syncthreads();
  #pragma unroll
  for (int st = NT/2; st > 0; st >>= 1){
    if (t < st) red[t] += red[t+st];
    __syncthreads();
  }
  float r = red[0]; __syncthreads();
  return r;
}
template<int NT>
__device__ inline float block_max(float v, float* red, int t){
  red[t] = v; __syncthreads();
  #pragma unroll
  for (int st = NT/2; st > 0; st >>= 1){
    if (t < st) red[t] = fmaxf(red[t], red[t+st]);
    __syncthreads();
  }
  float r = red[0]; __syncthreads();
  return r;
}
template<int NT>
__device__ inline int block_min_int(int v, int* red, int t){
  red[t] = v; __syncthreads();
  #pragma unroll
  for (int st = NT/2; st > 0; st >>= 1){
    if (t < st) red[t] = min(red[t], red[t+st]);
    __syncthreads();
  }
  int r = red[0]; __syncthreads();
  return r;
}

// ---------------- conv3x3(SAME), big-tile register-blocked ----------------
// Block: 256 threads = 4 waves. Block tile = 32x32 conv region (16x16 pooled).
// Lane -> quad (qx,qy in 8x8): thread computes conv points [4qy..4qy+3]x[4qx..4qx+3]
// (= 2x2 pooled outputs) for 2 couts (wave wv owns couts cg*8 + wv*2 + {0,1}).
// Per input channel: 18 ds_read_b64 (6x6 patch) + 10 weight reads -> 288 FMA.
// grid.z = SPLITK * (COUT/8). SPLITK==1: fused bias+relu+maxpool output [COUT][H/2][W/2].
// SPLITK>1: fp32 partial conv sums [split][COUT][H][W] (no bias/relu).
template<int CIN, int COUT, int SPLITK>
__global__ __launch_bounds__(256) void conv_big(
    const float* __restrict__ in, const float* __restrict__ w,
    const float* __restrict__ bias, float* __restrict__ out,
    int H, int W)
{
  constexpr int CPB   = CIN / SPLITK;
  constexpr int CHUNK = (CPB < 8) ? CPB : 8;
  constexpr int CGRPS = COUT / 8;
  __shared__ float tile[CHUNK][34][38];   // rows padded to 38 to spread banks
  __shared__ float wlds[8][CHUNK][10];    // 9 weights padded to 10 (b64-friendly)

  const int split = blockIdx.z / CGRPS;
  const int cg    = blockIdx.z % CGRPS;
  const int lane = threadIdx.x & 63;
  const int wv2  = (threadIdx.x >> 6) * 2;       // wave's first cout (of 2)
  const int qx = lane & 7, qy = lane >> 3;
  const int cy0 = 4*qy, cx0 = 4*qx;
  const int gy0 = 32*blockIdx.y - 1, gx0 = 32*blockIdx.x - 1;
  const int c_base = split * CPB;

  float acc[2][16];
  #pragma unroll
  for (int co=0;co<2;co++)
    #pragma unroll
    for (int i=0;i<16;i++) acc[co][i] = 0.f;

  for (int c0 = 0; c0 < CPB; c0 += CHUNK){
    __syncthreads();
    // stage input tile: CHUNK x 34 x 34 (cols 34..37 padding untouched)
    for (int e = threadIdx.x; e < CHUNK*1156; e += 256){
      int c   = e / 1156;
      int rem = e - c*1156;
      int row = rem / 34;
      int col = rem - row*34;
      int yy = gy0 + row, xx = gx0 + col;
      float v = 0.f;
      if ((unsigned)yy < (unsigned)H && (unsigned)xx < (unsigned)W)
        v = in[(size_t)(c_base + c0 + c)*H*W + (size_t)yy*W + xx];
      tile[c][row][col] = v;
    }
    // stage weights: 8 couts x CHUNK x 9
    for (int e = threadIdx.x; e < 8*CHUNK*9; e += 256){
      int co = e / (CHUNK*9);
      int r  = e - co*(CHUNK*9);
      int c  = r / 9;
      int k  = r - c*9;
      wlds[co][c][k] = w[((size_t)(cg*8 + co)*CIN + (c_base + c0 + c))*9 + k];
    }
    __syncthreads();

    #pragma unroll
    for (int c = 0; c < CHUNK; ++c){
      float p[6][6];
      #pragma unroll
      for (int i=0;i<6;i++){
        float2 a = *(const float2*)&tile[c][cy0+i][cx0];
        float2 b = *(const float2*)&tile[c][cy0+i][cx0+2];
        float2 d = *(const float2*)&tile[c][cy0+i][cx0+4];
        p[i][0]=a.x; p[i][1]=a.y; p[i][2]=b.x; p[i][3]=b.y; p[i][4]=d.x; p[i][5]=d.y;
      }
      float wg[2][9];
      #pragma unroll
      for (int co=0;co<2;co++){
        const float* wp = &wlds[wv2+co][c][0];
        float2 q0 = *(const float2*)&wp[0];
        float2 q1 = *(const float2*)&wp[2];
        float2 q2 = *(const float2*)&wp[4];
        float2 q3 = *(const float2*)&wp[6];
        wg[co][0]=q0.x; wg[co][1]=q0.y; wg[co][2]=q1.x; wg[co][3]=q1.y;
        wg[co][4]=q2.x; wg[co][5]=q2.y; wg[co][6]=q3.x; wg[co][7]=q3.y;
        wg[co][8]=wp[8];
      }
      #pragma unroll
      for (int co=0;co<2;co++)
        #pragma unroll
        for (int yy=0;yy<4;yy++)
          #pragma unroll
          for (int xx=0;xx<4;xx++){
            acc[co][yy*4+xx] +=
                wg[co][0]*p[yy  ][xx] + wg[co][1]*p[yy  ][xx+1] + wg[co][2]*p[yy  ][xx+2]
              + wg[co][3]*p[yy+1][xx] + wg[co][4]*p[yy+1][xx+1] + wg[co][5]*p[yy+1][xx+2]
              + wg[co][6]*p[yy+2][xx] + wg[co][7]*p[yy+2][xx+1] + wg[co][8]*p[yy+2][xx+2];
          }
    }
  }

  if (SPLITK == 1){
    const int OW = W >> 1, OH = H >> 1;
    #pragma unroll
    for (int co=0;co<2;co++){
      int cout = cg*8 + wv2 + co;
      float b = bias[cout];
      #pragma unroll
      for (int py=0;py<2;py++)
        #pragma unroll
        for (int px=0;px<2;px++){
          int i00 = (2*py)*4 + 2*px;
          float m = fmaxf(fmaxf(acc[co][i00], acc[co][i00+1]),
                          fmaxf(acc[co][i00+4], acc[co][i00+5])) + b;
          int oy = 16*blockIdx.y + 2*qy + py;
          int ox = 16*blockIdx.x + 2*qx + px;
          out[(size_t)cout*OH*OW + (size_t)oy*OW + ox] = fmaxf(m, 0.f);
        }
    }
  } else {
    #pragma unroll
    for (int co=0;co<2;co++){
      int cout = cg*8 + wv2 + co;
      float* pb = out + ((size_t)split*COUT + cout)*H*W;
      #pragma unroll
      for (int yy=0;yy<4;yy++){
        int gy = 32*blockIdx.y + cy0 + yy;
        int gx = 32*blockIdx.x + cx0;
        float4 v = make_float4(acc[co][yy*4+0], acc[co][yy*4+1],
                               acc[co][yy*4+2], acc[co][yy*4+3]);
        *(float4*)&pb[(size_t)gy*W + gx] = v;
      }
    }
  }
}

// sum fp32 partials over splits, then bias + relu + maxpool2x2
template<int SPLITK>
__global__ __launch_bounds__(256) void reduce_pool(
    const float* __restrict__ pbuf, const float* __restrict__ bias,
    float* __restrict__ out, int COUT, int H, int W)
{
  int idx = blockIdx.x*256 + threadIdx.x;
  const int OW = W >> 1, OH = H >> 1;
  if (idx >= COUT*OH*OW) return;
  int px = idx % OW; int t = idx / OW; int py = t % OH; int cout = t / OH;
  size_t base = (size_t)cout*H*W + (size_t)(2*py)*W + 2*px;
  size_t sstr = (size_t)COUT*H*W;
  float s00=0.f, s01=0.f, s10=0.f, s11=0.f;
  #pragma unroll
  for (int s=0;s<SPLITK;s++){
    const float* pb = pbuf + s*sstr + base;
    s00 += pb[0]; s01 += pb[1]; s10 += pb[W]; s11 += pb[W+1];
  }
  float m = fmaxf(fmaxf(s00,s01),fmaxf(s10,s11)) + bias[cout];
  out[idx] = fmaxf(m, 0.f);
}

// ---------------- graph kernels ----------------
__global__ void build_adj_kernel(const int* __restrict__ ei, float* adj, float* cnt){
  int e = blockIdx.x*256 + threadIdx.x;
  if (e < N_EDGES){
    int s = ei[e], d = ei[N_EDGES + e];
    atomicAdd(&adj[s*NN1 + d], 1.0f);   // integer-valued -> order independent
    atomicAdd(&cnt[d], 1.0f);
  }
}

__global__ __launch_bounds__(256) void agg_kernel(const float* __restrict__ adj,
    const float* __restrict__ cnt, const float* __restrict__ org, float* __restrict__ aggn){
  int d = blockIdx.x, j = threadIdx.x;
  float acc = 0.f;
  for (int s = 0; s < NN1; ++s){
    float a = adj[s*NN1 + d];
    if (a != 0.f) acc += a * org[s*NN1 + j];
  }
  aggn[d*NN1 + j] = acc / fmaxf(cnt[d], 1.0f);
}

__global__ __launch_bounds__(128) void sage12_kernel(
    const float* __restrict__ aggn, const float* __restrict__ org,
    const float* __restrict__ wl1, const float* __restrict__ bl1, const float* __restrict__ wr1,
    const float* __restrict__ wl2, const float* __restrict__ bl2, const float* __restrict__ wr2,
    float* __restrict__ x1, float* __restrict__ s_out, float* __restrict__ entpart)
{
  __shared__ float sa[NN1], so[NN1], red[128];
  int n = blockIdx.x, c = threadIdx.x;
  for (int k = c; k < NN1; k += 128){ sa[k] = aggn[n*NN1+k]; so[k] = org[n*NN1+k]; }
  __syncthreads();
  float p1 = bl1[c], p2 = bl2[c];
  const float* wl1r = wl1 + c*NN1; const float* wr1r = wr1 + c*NN1;
  const float* wl2r = wl2 + c*NN1; const float* wr2r = wr2 + c*NN1;
  for (int k = 0; k < NN1; ++k){
    float av = sa[k], ov = so[k];
    p1 += av*wl1r[k] + ov*wr1r[k];
    p2 += av*wl2r[k] + ov*wr2r[k];
  }
  float n1s = block_sum<128>(p1*p1, red, c);
  x1[n*128 + c] = p1 / fmaxf(sqrtf(n1s), 1e-12f);
  float n2s = block_sum<128>(p2*p2, red, c);
  float p2n = p2 / fmaxf(sqrtf(n2s), 1e-12f);
  float mx = block_max<128>(p2n, red, c);
  float ev = expf(p2n - mx);
  float ssum = block_sum<128>(ev, red, c);
  float sv = ev / ssum;
  s_out[n*128 + c] = sv;
  float esum = block_sum<128>(-sv * logf(sv + 1e-15f), red, c);
  if (c == 0) entpart[n] = esum;
}

__global__ __launch_bounds__(128) void xp_kernel(const float* __restrict__ s,
    const float* __restrict__ x1, float* __restrict__ xp){
  int cc = blockIdx.x, f = threadIdx.x;
  float acc = 0.f;
  for (int n = 0; n < NN1; ++n) acc += s[n*128+cc] * x1[n*128+f];
  xp[cc*128+f] = acc;
}

__global__ __launch_bounds__(128) void adj_s_kernel(const float* __restrict__ adj,
    const float* __restrict__ s, float* __restrict__ t){
  int n = blockIdx.x, c = threadIdx.x;
  float acc = 0.f;
  for (int m = 0; m < NN1; ++m){
    float a = adj[n*NN1+m];
    if (a != 0.f) acc += a * s[m*128+c];
  }
  t[n*128+c] = acc;
}

__global__ __launch_bounds__(128) void adjp_kernel(const float* __restrict__ s,
    const float* __restrict__ t, float* __restrict__ adjp){
  int cc = blockIdx.x, d = threadIdx.x;
  float acc = 0.f;
  for (int n = 0; n < NN1; ++n) acc += s[n*128+cc] * t[n*128+d];
  adjp[cc*128+d] = acc;
}

__global__ __launch_bounds__(256) void link_kernel(const float* __restrict__ adj,
    const float* __restrict__ s, float* __restrict__ linkpart){
  __shared__ float sn[128]; __shared__ float red[256];
  int n = blockIdx.x, m = threadIdx.x;
  if (m < 128) sn[m] = s[n*128+m];
  __syncthreads();
  float dot = 0.f;
  const float* sm = s + m*128;
  for (int c = 0; c < 128; ++c) dot += sn[c]*sm[c];
  float v = adj[n*NN1+m] - dot;
  float part = block_sum<256>(v*v, red, m);
  if (m == 0) linkpart[n] = part;
}

__global__ __launch_bounds__(128) void binarize_kernel(const float* __restrict__ adjp,
    float* __restrict__ edge_out, float* __restrict__ ei2_out, int* __restrict__ cols){
  __shared__ float red[128]; __shared__ int redi[128];
  int i = blockIdx.x, j = threadIdx.x;
  float v = adjp[i*128+j];
  float mx = block_max<128>(v, red, j);
  edge_out[i*128+j] = (v == mx) ? 1.0f : 0.0f;
  int cand = (v == mx) ? j : (1 << 30);
  int cmin = block_min_int<128>(cand, redi, j);
  if (j == 0){
    cols[i] = cmin;
    ei2_out[i] = (float)i;
    ei2_out[128 + i] = (float)cmin;
  }
}

__global__ __launch_bounds__(128) void sage3_agg_kernel(const float* __restrict__ xp,
    const int* __restrict__ cols, float* __restrict__ aggn3){
  int d = blockIdx.x, f = threadIdx.x;
  float acc = 0.f, c = 0.f;
  for (int i = 0; i < NN2; ++i){
    if (cols[i] == d){ acc += xp[i*128+f]; c += 1.f; }
  }
  aggn3[d*128+f] = acc / fmaxf(c, 1.f);
}

__global__ __launch_bounds__(128) void sage3_out_kernel(const float* __restrict__ aggn3,
    const float* __restrict__ xp,
    const float* __restrict__ wl3, const float* __restrict__ bl3, const float* __restrict__ wr3,
    float* __restrict__ nodes_out)
{
  __shared__ float red[128];
  int n = blockIdx.x, k = threadIdx.x;
  float ag = aggn3[n*128+k];
  float xv = xp[n*128+k];
  float q0 = block_sum<128>(ag*wl3[k]     + xv*wr3[k],     red, k);
  float q1 = block_sum<128>(ag*wl3[128+k] + xv*wr3[128+k], red, k);
  if (k == 0){
    float p0 = q0 + bl3[0], p1 = q1 + bl3[1];
    float nm = fmaxf(sqrtf(p0*p0 + p1*p1), 1e-12f);
    nodes_out[n*2+0] = tanhf(p0/nm);
    nodes_out[n*2+1] = tanhf(p1/nm);
  }
}

__global__ __launch_bounds__(256) void finalize_kernel(const float* __restrict__ linkpart,
    const float* __restrict__ entpart, float* __restrict__ d_out)
{
  __shared__ float red[256];
  int t = threadIdx.x;
  float ls = block_sum<256>(linkpart[t], red, t);
  float es = block_sum<256>(entpart[t], red, t);
  float v0 = 0.f, v1 = 0.f;
  if (t < 128){ v0 = d_out[4 + t*2 + 0]; v1 = d_out[4 + t*2 + 1]; }
  float s0 = block_sum<256>(v0, red, t);
  float s1 = block_sum<256>(v1, red, t);
  if (t == 0){
    d_out[0] = s0;
    d_out[1] = s1;
    d_out[2] = sqrtf(ls)/65536.0f + sqrtf(16256.0f)/16384.0f;  // ll1 + ll2(const)
    d_out[3] = es/256.0f;                                      // el1 + el2(=0)
  }
}

extern "C" void kernel_launch(void* const* d_in, const int* in_sizes, int n_in,
                              void* d_out_v, int out_size, void* d_ws, size_t ws_size,
                              hipStream_t stream)
{
  (void)in_sizes; (void)n_in; (void)out_size; (void)ws_size;
  const float* input = (const float*)d_in[0];
  const int*   ei    = (const int*)  d_in[1];
  const float* w1 = (const float*)d_in[2];  const float* b1 = (const float*)d_in[3];
  const float* w2 = (const float*)d_in[4];  const float* b2 = (const float*)d_in[5];
  const float* w3 = (const float*)d_in[6];  const float* b3 = (const float*)d_in[7];
  const float* w4 = (const float*)d_in[8];  const float* b4 = (const float*)d_in[9];
  const float* w5 = (const float*)d_in[10]; const float* b5 = (const float*)d_in[11];
  const float* s1wl = (const float*)d_in[12]; const float* s1bl = (const float*)d_in[13];
  const float* s1wr = (const float*)d_in[14];
  const float* s2wl = (const float*)d_in[15]; const float* s2bl = (const float*)d_in[16];
  const float* s2wr = (const float*)d_in[17];
  const float* s3wl = (const float*)d_in[18]; const float* s3bl = (const float*)d_in[19];
  const float* s3wr = (const float*)d_in[20];
  float* d_out = (float*)d_out_v;
  float* ws = (float*)d_ws;

  // workspace layout (floats), total 5,308,416 = 21.2 MB (same as proven r2 footprint)
  // P        [0, 4194304)       fp32 split-K partials (L3/L4/L5), time-shared
  // L1out    [0, 2097152)       alias of P (dead before P first written)
  // L2out    [4194304, 5242880)
  // L3out    [4194304, 4718592) alias (written after L2out dead)
  // L4out    [4194304, 4456448) alias (written after L3out dead)
  // org      [5242880, 5308416)
  // graph scratch aliases P after convs
  float* P     = ws;
  float* L1out = ws;
  float* L2out = ws + 4194304;
  float* L3out = ws + 4194304;
  float* L4out = ws + 4194304;
  float* org   = ws + 5242880;

  float* adj1     = P;                   // 65,536
  float* cnt      = P + 65536;           // 256
  float* aggn3    = P + 65792;           // 16,384
  float* aggn     = P + 82176;           // 65,536
  float* x1       = P + 147712;          // 32,768
  float* s        = P + 180480;          // 32,768
  float* t        = P + 213248;          // 32,768
  float* xp       = P + 246016;          // 16,384
  float* adjp     = P + 262400;          // 16,384
  int*   cols     = (int*)(P + 278784);  // 128
  float* linkpart = P + 278912;          // 256
  float* entpart  = P + 279168;          // 256

  // L1: 5->32 @512 fused -> L1out 32x256x256
  conv_big<5,32,1>     <<<dim3(16,16,4),   256, 0, stream>>>(input, w1, b1, L1out, 512, 512);
  // L2: 32->64 @256 fused -> L2out 64x128x128
  conv_big<32,64,1>    <<<dim3(8,8,8),     256, 0, stream>>>(L1out, w2, b2, L2out, 256, 256);
  // L3: 64->128 @128, splitk2 -> P, reduce -> L3out 128x64x64
  conv_big<64,128,2>   <<<dim3(4,4,32),    256, 0, stream>>>(L2out, w3, b3, P, 128, 128);
  reduce_pool<2>       <<<dim3(2048),      256, 0, stream>>>(P, b3, L3out, 128, 128, 128);
  // L4: 128->256 @64, splitk4 -> P, reduce -> L4out 256x32x32
  conv_big<128,256,4>  <<<dim3(2,2,128),   256, 0, stream>>>(L3out, w4, b4, P, 64, 64);
  reduce_pool<4>       <<<dim3(1024),      256, 0, stream>>>(P, b4, L4out, 256, 64, 64);
  // L5: 256->256 @32, splitk16 -> P, reduce -> org 256x16x16
  conv_big<256,256,16> <<<dim3(1,1,512),   256, 0, stream>>>(L4out, w5, b5, P, 32, 32);
  reduce_pool<16>      <<<dim3(256),       256, 0, stream>>>(P, b5, org, 256, 32, 32);

  // graph tail (P region now reusable as scratch)
  hipMemsetAsync(adj1, 0, (65536 + 256)*sizeof(float), stream);
  build_adj_kernel<<<dim3(16),  256, 0, stream>>>(ei, adj1, cnt);
  agg_kernel      <<<dim3(256), 256, 0, stream>>>(adj1, cnt, org, aggn);
  sage12_kernel   <<<dim3(256), 128, 0, stream>>>(aggn, org, s1wl, s1bl, s1wr,
                                                  s2wl, s2bl, s2wr, x1, s, entpart);
  xp_kernel       <<<dim3(128), 128, 0, stream>>>(s, x1, xp);
  adj_s_kernel    <<<dim3(256), 128, 0, stream>>>(adj1, s, t);
  adjp_kernel     <<<dim3(128), 128, 0, stream>>>(s, t, adjp);
  link_kernel     <<<dim3(256), 256, 0, stream>>>(adj1, s, linkpart);
  binarize_kernel <<<dim3(128), 128, 0, stream>>>(adjp, d_out + 260, d_out + 16644, cols);
  sage3_agg_kernel<<<dim3(128), 128, 0, stream>>>(xp, cols, aggn3);
  sage3_out_kernel<<<dim3(128), 128, 0, stream>>>(aggn3, xp, s3wl, s3bl, s3wr, d_out + 4);
  finalize_kernel <<<dim3(1),   256, 0, stream>>>(linkpart, entpart, d_out);
}